// Round 1
// baseline (64.535 us; speedup 1.0000x reference)
//
#include <hip/hip_runtime.h>
#include <math.h>

// FocalCTCloss — MI355X (gfx950)
// T=160, N=128, C=6625, S=32, L=2S+1=65, blank=0
// Structure: per-sample block gathers lp_ext[T][L] (41.6 KB) into LDS once,
// then runs the CTC alpha recursion entirely in LDS. Second kernel reduces.

#define TT 160
#define NN 128
#define CC 6625
#define SS 32
#define LL 65          // 2*SS + 1
#define NEGV (-1e30f)

__global__ __launch_bounds__(256) void ctc_alpha_kernel(
    const float* __restrict__ log_probs,     // [T, N, C]
    const int*   __restrict__ targets,       // [N, S]
    const int*   __restrict__ input_lengths, // [N]
    const int*   __restrict__ target_lengths,// [N]
    float*       __restrict__ per_sample)    // [N]  loss/target_length
{
    const int n   = blockIdx.x;
    const int tid = threadIdx.x;

    __shared__ float lp[TT * LL];          // 41600 B
    __shared__ float albuf[2][LL + 2];     // double-buffered alpha, 2 pad slots in front
    __shared__ int   ext_s[LL];
    __shared__ unsigned char skip_s[LL];

    const int tl   = target_lengths[n];
    const int ilen = input_lengths[n];

    // ---- build extended target: even = blank(0), odd = targets[n][(l-1)/2]
    if (tid < LL) {
        int e = 0;
        if (tid & 1) e = targets[n * SS + (tid >> 1)];
        ext_s[tid] = e;
    }
    __syncthreads();
    if (tid < LL) {
        int e = ext_s[tid];
        skip_s[tid] = (tid >= 2) && (e != 0) && (e != ext_s[tid - 2]);
    }
    __syncthreads();

    // ---- gather lp_ext[t][l] = log_probs[t, n, ext[l]] into LDS
    const long long rowbase = (long long)n * CC;
    const long long tstride = (long long)NN * CC;
#pragma unroll 4
    for (int i = tid; i < TT * LL; i += 256) {
        int t = i / LL;
        int l = i - t * LL;
        lp[i] = log_probs[(long long)t * tstride + rowbase + ext_s[l]];
    }
    __syncthreads();

    // ---- alpha at t=0 (pads at indices 0,1 stay NEGV in both buffers)
    if (tid < LL + 2) {
        float a = NEGV;
        int l = tid - 2;
        if (l == 0) a = lp[0];       // blank at position 0
        if (l == 1) a = lp[1];       // first label
        albuf[0][tid] = a;
        albuf[1][tid] = NEGV;
    }
    __syncthreads();

    const int  l      = tid;
    const bool act    = (tid < LL);
    const bool validl = act && (l < 2 * tl + 1);
    const bool cskip  = act && (skip_s[act ? l : 0] != 0);

    const int Tlim = (ilen < TT) ? ilen : TT;
    int p = 0;
    for (int t = 1; t < Tlim; ++t) {
        float nv = NEGV;
        if (act) {
            float a1 = albuf[p][l + 2];
            float a2 = albuf[p][l + 1];
            float a3 = cskip ? albuf[p][l] : NEGV;
            float m  = fmaxf(a1, fmaxf(a2, a3));
            nv = m + logf(expf(a1 - m) + expf(a2 - m) + expf(a3 - m)) + lp[t * LL + l];
            if (!validl) nv = NEGV;
        }
        // reads of buf[p] above happen before this sync; writes to buf[p^1]
        // become visible after it; buf[p] is only overwritten next iter
        // (which is after this sync), so one sync per step suffices... but
        // the write below must ALSO complete before next iter's reads of
        // buf[p^1]; hence: write, then sync.
        if (act) albuf[p ^ 1][l + 2] = nv;
        __syncthreads();
        p ^= 1;
    }

    if (tid == 0) {
        int i1 = 2 * tl;
        int i2 = 2 * tl - 1;
        float a1 = albuf[p][i1 + 2];
        float a2 = albuf[p][i2 + 2];
        float m  = fmaxf(a1, a2);
        float loss = -(m + logf(expf(a1 - m) + expf(a2 - m)));
        if (loss > 1e29f) loss = 0.0f;     // zero_infinity
        per_sample[n] = loss / (float)tl;
    }
}

__global__ __launch_bounds__(128) void focal_reduce_kernel(
    const float* __restrict__ per_sample, float* __restrict__ out)
{
    __shared__ float s[NN];
    int tid = threadIdx.x;
    s[tid] = per_sample[tid];
    __syncthreads();
    for (int off = NN / 2; off > 0; off >>= 1) {
        if (tid < off) s[tid] += s[tid + off];
        __syncthreads();
    }
    if (tid == 0) {
        float mean = s[0] / (float)NN;         // reduction='mean'
        float pp = expf(-mean);
        float om = 1.0f - pp;
        out[0] = 0.5f * om * om * mean;        // ALPHA=0.5, GAMMA=2.0
    }
}

extern "C" void kernel_launch(void* const* d_in, const int* in_sizes, int n_in,
                              void* d_out, int out_size, void* d_ws, size_t ws_size,
                              hipStream_t stream) {
    const float* log_probs      = (const float*)d_in[0];
    const int*   targets        = (const int*)d_in[1];
    const int*   input_lengths  = (const int*)d_in[2];
    const int*   target_lengths = (const int*)d_in[3];
    float* per_sample = (float*)d_ws;   // NN floats
    float* out        = (float*)d_out;

    ctc_alpha_kernel<<<NN, 256, 0, stream>>>(log_probs, targets, input_lengths,
                                             target_lengths, per_sample);
    focal_reduce_kernel<<<1, NN, 0, stream>>>(per_sample, out);
}

// Round 2
// 53.376 us; speedup vs baseline: 1.2091x; 1.2091x over previous
//
#include <hip/hip_runtime.h>
#include <math.h>

// FocalCTCloss — MI355X (gfx950)
// T=160, N=128, C=6625, S=32, L=2S+1=65, blank=0
// Pipeline: (A) full-device scatter-gather of lp_ext[N][T][L] into ws,
//           (B) per-sample block: float4-stage 41.6KB into LDS, then wave-0
//               register/shuffle alpha recursion (no barriers in the loop),
//           (C) deterministic reduce + focal transform.

#define TT 160
#define NN 128
#define CC 6625
#define SS 32
#define LL 65          // 2*SS + 1
#define NTL (NN * TT * LL)   // 1,331,200
#define NEGV (-1e30f)

// ---------------- Kernel A: gather lp_ext into ws ----------------
__global__ __launch_bounds__(256) void gather_kernel(
    const float* __restrict__ log_probs,   // [T, N, C]
    const int*   __restrict__ targets,     // [N, S]
    float*       __restrict__ lp_ws)       // [N, T, L]
{
    const int i = blockIdx.x * 256 + threadIdx.x;   // grid sized exactly NTL/256
    const int n = i / (TT * LL);
    const int r = i - n * (TT * LL);
    const int t = r / LL;
    const int l = r - t * LL;
    const int label = (l & 1) ? targets[n * SS + (l >> 1)] : 0;
    lp_ws[i] = log_probs[(size_t)t * (NN * CC) + n * CC + label];
}

// ---------------- Kernel B: alpha recursion (shuffle scan) ----------------
__global__ __launch_bounds__(256) void alpha_scan_kernel(
    const float* __restrict__ lp_ws,          // [N, T, L]
    const int*   __restrict__ targets,        // [N, S]
    const int*   __restrict__ input_lengths,  // [N]
    const int*   __restrict__ target_lengths, // [N]
    float*       __restrict__ per_sample)     // [N]
{
    const int n   = blockIdx.x;
    const int tid = threadIdx.x;

    __shared__ float lp[TT * LL];   // 41600 B

    // stage this sample's lattice (contiguous, float4) into LDS
    const float4* src = (const float4*)(lp_ws + n * (TT * LL));
    float4* dst = (float4*)lp;
#pragma unroll
    for (int k = tid; k < (TT * LL) / 4; k += 256) dst[k] = src[k];
    __syncthreads();

    if (tid >= 64) return;          // wave 0 only from here; no more barriers
    const int lane = tid;

    const int tl = target_lengths[n];
    const int Lv = 2 * tl + 1;
    // skip flag: odd l >= 3 and label != label two back
    const bool skip = (lane & 1) && (lane >= 3) &&
                      (targets[n * SS + (lane >> 1)] != targets[n * SS + (lane >> 1) - 1]);
    const bool validl  = lane < Lv;
    const bool valid64 = 64 < Lv;

    // alpha at t=0; lane holds l=lane, lane 63 additionally holds l=64 in `e`
    float v = NEGV;
    if (lane == 0) v = lp[0];
    if (lane == 1) v = lp[1];
    float e = NEGV;

    const int ilen = input_lengths[n];
    const int Tlim = (ilen < TT) ? ilen : TT;

    for (int t = 1; t < Tlim; ++t) {
        const float u1 = __shfl_up(v, 1);
        const float u2 = __shfl_up(v, 2);
        const float a2 = (lane == 0) ? NEGV : u1;
        const float a3 = skip ? u2 : NEGV;

        // l = 64 (blank, never skip) on lane 63, using OLD v (= alpha[63])
        const float lpt64 = lp[t * LL + 64];
        const float me = fmaxf(e, v);
        const float ne = me + __logf(__expf(e - me) + __expf(v - me) + __expf(NEGV - me)) + lpt64;

        const float m  = fmaxf(v, fmaxf(a2, a3));
        const float nv = m + __logf(__expf(v - m) + __expf(a2 - m) + __expf(a3 - m))
                           + lp[t * LL + lane];

        v = validl  ? nv : NEGV;
        e = valid64 ? ne : NEGV;
    }

    const int i1 = 2 * tl;
    const int i2 = 2 * tl - 1;
    const float A1 = (i1 == 64) ? __shfl(e, 63) : __shfl(v, i1);
    const float A2 = __shfl(v, i2);
    if (lane == 0) {
        const float m = fmaxf(A1, A2);
        float loss = -(m + __logf(__expf(A1 - m) + __expf(A2 - m)));
        if (loss > 1e29f) loss = 0.0f;    // zero_infinity
        per_sample[n] = loss / (float)tl;
    }
}

// ---------------- Fallback (round-1 kernel, used if ws too small) ----------------
__global__ __launch_bounds__(256) void ctc_alpha_kernel(
    const float* __restrict__ log_probs,
    const int*   __restrict__ targets,
    const int*   __restrict__ input_lengths,
    const int*   __restrict__ target_lengths,
    float*       __restrict__ per_sample)
{
    const int n   = blockIdx.x;
    const int tid = threadIdx.x;

    __shared__ float lp[TT * LL];
    __shared__ float albuf[2][LL + 2];
    __shared__ int   ext_s[LL];
    __shared__ unsigned char skip_s[LL];

    const int tl   = target_lengths[n];
    const int ilen = input_lengths[n];

    if (tid < LL) {
        int ee = 0;
        if (tid & 1) ee = targets[n * SS + (tid >> 1)];
        ext_s[tid] = ee;
    }
    __syncthreads();
    if (tid < LL) {
        int ee = ext_s[tid];
        skip_s[tid] = (tid >= 2) && (ee != 0) && (ee != ext_s[tid - 2]);
    }
    __syncthreads();

    const long long rowbase = (long long)n * CC;
    const long long tstride = (long long)NN * CC;
#pragma unroll 4
    for (int i = tid; i < TT * LL; i += 256) {
        int t = i / LL;
        int l = i - t * LL;
        lp[i] = log_probs[(long long)t * tstride + rowbase + ext_s[l]];
    }
    __syncthreads();

    if (tid < LL + 2) {
        float a = NEGV;
        int l = tid - 2;
        if (l == 0) a = lp[0];
        if (l == 1) a = lp[1];
        albuf[0][tid] = a;
        albuf[1][tid] = NEGV;
    }
    __syncthreads();

    const int  l      = tid;
    const bool act    = (tid < LL);
    const bool validl = act && (l < 2 * tl + 1);
    const bool cskip  = act && (skip_s[act ? l : 0] != 0);

    const int Tlim = (ilen < TT) ? ilen : TT;
    int p = 0;
    for (int t = 1; t < Tlim; ++t) {
        float nv = NEGV;
        if (act) {
            float a1 = albuf[p][l + 2];
            float a2 = albuf[p][l + 1];
            float a3 = cskip ? albuf[p][l] : NEGV;
            float m  = fmaxf(a1, fmaxf(a2, a3));
            nv = m + logf(expf(a1 - m) + expf(a2 - m) + expf(a3 - m)) + lp[t * LL + l];
            if (!validl) nv = NEGV;
        }
        if (act) albuf[p ^ 1][l + 2] = nv;
        __syncthreads();
        p ^= 1;
    }

    if (tid == 0) {
        int i1 = 2 * tl;
        int i2 = 2 * tl - 1;
        float a1 = albuf[p][i1 + 2];
        float a2 = albuf[p][i2 + 2];
        float m  = fmaxf(a1, a2);
        float loss = -(m + logf(expf(a1 - m) + expf(a2 - m)));
        if (loss > 1e29f) loss = 0.0f;
        per_sample[n] = loss / (float)tl;
    }
}

// ---------------- Kernel C: reduce + focal ----------------
__global__ __launch_bounds__(128) void focal_reduce_kernel(
    const float* __restrict__ per_sample, float* __restrict__ out)
{
    __shared__ float s[NN];
    int tid = threadIdx.x;
    s[tid] = per_sample[tid];
    __syncthreads();
    for (int off = NN / 2; off > 0; off >>= 1) {
        if (tid < off) s[tid] += s[tid + off];
        __syncthreads();
    }
    if (tid == 0) {
        float mean = s[0] / (float)NN;
        float pp = expf(-mean);
        float om = 1.0f - pp;
        out[0] = 0.5f * om * om * mean;   // ALPHA=0.5, GAMMA=2.0
    }
}

extern "C" void kernel_launch(void* const* d_in, const int* in_sizes, int n_in,
                              void* d_out, int out_size, void* d_ws, size_t ws_size,
                              hipStream_t stream) {
    const float* log_probs      = (const float*)d_in[0];
    const int*   targets        = (const int*)d_in[1];
    const int*   input_lengths  = (const int*)d_in[2];
    const int*   target_lengths = (const int*)d_in[3];
    float* out = (float*)d_out;

    float* per_sample = (float*)d_ws;                          // 128 floats
    float* lp_ws      = (float*)((char*)d_ws + 1024);          // NTL floats

    const size_t need = 1024 + (size_t)NTL * sizeof(float);
    if (ws_size >= need) {
        gather_kernel<<<NTL / 256, 256, 0, stream>>>(log_probs, targets, lp_ws);
        alpha_scan_kernel<<<NN, 256, 0, stream>>>(lp_ws, targets, input_lengths,
                                                  target_lengths, per_sample);
    } else {
        ctc_alpha_kernel<<<NN, 256, 0, stream>>>(log_probs, targets, input_lengths,
                                                 target_lengths, per_sample);
    }
    focal_reduce_kernel<<<1, NN, 0, stream>>>(per_sample, out);
}

// Round 3
// 52.131 us; speedup vs baseline: 1.2379x; 1.0239x over previous
//
#include <hip/hip_runtime.h>
#include <math.h>

// FocalCTCloss — MI355X (gfx950)
// T=160, N=128, C=6625, S=32, L=2S+1=65, blank=0
// Pipeline:
//   (A) gather the 33 UNIQUE log-probs per (n,t) (blank + 32 labels) into
//       ws as lp_u[N][T][33], pre-scaled by log2(e)  — 1024 blocks, full MLP
//   (B) per-sample block: float4-stage 21.1KB into LDS, wave-0 shuffle scan
//       in log2 domain (no barriers, native v_exp/v_log)
//   (C) deterministic reduce + focal transform.

#define TT 160
#define NN 128
#define CC 6625
#define SS 32
#define LL 65            // 2*SS + 1
#define JJ 33            // unique labels per (n,t): blank + 32
#define NEGV  (-1e30f)
#define LOG2E 1.4426950408889634f
#define LN2   0.6931471805599453f

// ---------------- Kernel A: gather unique lattice columns ----------------
__global__ __launch_bounds__(256) void gather_kernel(
    const float* __restrict__ log_probs,   // [T, N, C]
    const int*   __restrict__ targets,     // [N, S]
    float*       __restrict__ lp_u)        // [N, T, JJ], pre-scaled by log2e
{
    __shared__ int lab[JJ];
    const int n  = blockIdx.x >> 3;        // 128 samples
    const int ch = blockIdx.x & 7;         // 8 chunks of 20 t-steps
    const int tid = threadIdx.x;

    if (tid < JJ) lab[tid] = (tid == 0) ? 0 : targets[n * SS + tid - 1];
    __syncthreads();

    const int t0 = ch * 20;
    const size_t outbase = (size_t)n * (TT * JJ) + (size_t)t0 * JJ;
#pragma unroll
    for (int i = tid; i < 20 * JJ; i += 256) {           // 660 elements
        const int t = t0 + i / JJ;
        const int j = i - (i / JJ) * JJ;
        const float v = log_probs[(size_t)t * (NN * CC) + (size_t)n * CC + lab[j]];
        lp_u[outbase + i] = v * LOG2E;
    }
}

// ---------------- Kernel B: alpha recursion (shuffle scan, log2 domain) ----------------
__global__ __launch_bounds__(256) void alpha_scan_kernel(
    const float* __restrict__ lp_u,           // [N, T, JJ] scaled by log2e
    const int*   __restrict__ targets,        // [N, S]
    const int*   __restrict__ input_lengths,  // [N]
    const int*   __restrict__ target_lengths, // [N]
    float*       __restrict__ per_sample)     // [N]
{
    const int n   = blockIdx.x;
    const int tid = threadIdx.x;

    __shared__ float lp[TT * JJ];   // 5280 floats = 21.1 KB

    const float4* src = (const float4*)(lp_u + (size_t)n * (TT * JJ));
    float4* dst = (float4*)lp;
#pragma unroll
    for (int k = tid; k < (TT * JJ) / 4; k += 256) dst[k] = src[k];  // 1320
    __syncthreads();

    if (tid >= 64) return;          // wave 0 only; no more barriers
    const int lane = tid;

    const int tl = target_lengths[n];
    const int Lv = 2 * tl + 1;
    // lane l's slot in the unique-column row: even->blank(0), odd->1+(l>>1)
    const int slot = (lane & 1) ? (1 + (lane >> 1)) : 0;
    const bool skip = (lane & 1) && (lane >= 3) &&
                      (targets[n * SS + (lane >> 1)] != targets[n * SS + (lane >> 1) - 1]);
    const bool validl  = lane < Lv;
    const bool valid64 = 64 < Lv;

    // alpha (log2-scaled); lane l holds l, lane 63 also holds l=64 in `e`
    float v = NEGV;
    if (lane == 0) v = lp[0];        // t=0, blank
    if (lane == 1) v = lp[1];        // t=0, first label
    float e = NEGV;

    const int ilen = input_lengths[n];
    const int Tlim = (ilen < TT) ? ilen : TT;

    for (int t = 1; t < Tlim; ++t) {
        const float u1 = __shfl_up(v, 1);
        const float u2 = __shfl_up(v, 2);
        const float a2 = (lane == 0) ? NEGV : u1;
        const float a3 = skip ? u2 : NEGV;

        // l = 64 (blank, never skip) on lane 63, using OLD v (= alpha[63])
        const float lpt64 = lp[t * JJ];          // slot 0, uniform -> broadcast
        const float me = fmaxf(e, v);
        const float ne = me + log2f(exp2f(e - me) + exp2f(v - me)) + lpt64;

        const float m  = fmaxf(v, fmaxf(a2, a3));
        const float nv = m + log2f(exp2f(v - m) + exp2f(a2 - m) + exp2f(a3 - m))
                           + lp[t * JJ + slot];

        v = validl  ? nv : NEGV;
        e = valid64 ? ne : NEGV;
    }

    const int i1 = 2 * tl;
    const int i2 = 2 * tl - 1;
    const float A1 = (i1 == 64) ? __shfl(e, 63) : __shfl(v, i1);
    const float A2 = __shfl(v, i2);
    if (lane == 0) {
        const float m = fmaxf(A1, A2);
        float loss = -LN2 * (m + log2f(exp2f(A1 - m) + exp2f(A2 - m)));
        if (loss > 1e29f) loss = 0.0f;    // zero_infinity
        per_sample[n] = loss / (float)tl;
    }
}

// ---------------- Kernel C: reduce + focal ----------------
__global__ __launch_bounds__(128) void focal_reduce_kernel(
    const float* __restrict__ per_sample, float* __restrict__ out)
{
    __shared__ float s[NN];
    int tid = threadIdx.x;
    s[tid] = per_sample[tid];
    __syncthreads();
    for (int off = NN / 2; off > 0; off >>= 1) {
        if (tid < off) s[tid] += s[tid + off];
        __syncthreads();
    }
    if (tid == 0) {
        float mean = s[0] / (float)NN;
        float pp = expf(-mean);
        float om = 1.0f - pp;
        out[0] = 0.5f * om * om * mean;   // ALPHA=0.5, GAMMA=2.0
    }
}

extern "C" void kernel_launch(void* const* d_in, const int* in_sizes, int n_in,
                              void* d_out, int out_size, void* d_ws, size_t ws_size,
                              hipStream_t stream) {
    const float* log_probs      = (const float*)d_in[0];
    const int*   targets        = (const int*)d_in[1];
    const int*   input_lengths  = (const int*)d_in[2];
    const int*   target_lengths = (const int*)d_in[3];
    float* out = (float*)d_out;

    float* per_sample = (float*)d_ws;                       // 128 floats
    float* lp_u       = (float*)((char*)d_ws + 1024);       // N*T*JJ floats

    gather_kernel<<<NN * 8, 256, 0, stream>>>(log_probs, targets, lp_u);
    alpha_scan_kernel<<<NN, 256, 0, stream>>>(lp_u, targets, input_lengths,
                                              target_lengths, per_sample);
    focal_reduce_kernel<<<1, NN, 0, stream>>>(per_sample, out);
}

// Round 4
// 48.308 us; speedup vs baseline: 1.3359x; 1.0791x over previous
//
#include <hip/hip_runtime.h>
#include <math.h>

// FocalCTCloss — MI355X (gfx950)
// T=160, N=128, C=6625, S=32, L=2S+1=65, blank=0
// Fused design:
//   Kernel 1 (128 blocks x 1024 thr): 16 waves gather the 33 unique
//     log-probs per t (blank + 32 labels) straight into LDS (5280 scattered
//     loads, full MLP), one barrier, then wave 0 runs the 159-step alpha
//     recursion with DPP lane-shifts (no ds_bpermute on the serial chain),
//     log2 domain (native v_exp/v_log).
//   Kernel 2: deterministic reduce + focal transform.

#define TT 160
#define NN 128
#define CC 6625
#define SS 32
#define JJ 33            // unique labels per (n,t): blank + 32
#define NEGV  (-1e30f)
#define LOG2E 1.4426950408889634f
#define LN2   0.6931471805599453f

// wave64 shift-up-by-1 via DPP: row_shr:1, boundary lanes (16k) patched with
// row_bcast15 (lane 16r-1 -> row r). Lane 0 result is garbage (own value) —
// callers mask lane 0 / lanes<3 explicitly.
__device__ __forceinline__ float dpp_up1(float x, bool row0lane) {
    int xi = __float_as_int(x);
    int shr = __builtin_amdgcn_update_dpp(xi, xi, 0x111, 0xf, 0xf, false); // row_shr:1
    int bc  = __builtin_amdgcn_update_dpp(xi, xi, 0x142, 0xf, 0xf, false); // row_bcast15
    return __int_as_float(row0lane ? bc : shr);
}

__global__ __launch_bounds__(1024) void ctc_fused_kernel(
    const float* __restrict__ log_probs,      // [T, N, C]
    const int*   __restrict__ targets,        // [N, S]
    const int*   __restrict__ input_lengths,  // [N]
    const int*   __restrict__ target_lengths, // [N]
    float*       __restrict__ per_sample)     // [N]
{
    const int n   = blockIdx.x;
    const int tid = threadIdx.x;

    __shared__ float lp[TT * JJ];   // 5280 floats = 21.1 KB, log2-scaled
    __shared__ int   lab[JJ];       // slot 0 = blank, slot j = targets[j-1]

    if (tid < JJ) lab[tid] = (tid == 0) ? 0 : targets[n * SS + tid - 1];
    __syncthreads();

    // ---- gather: 5280 scattered loads, 6 predicated per thread ----
    const size_t rowbase = (size_t)n * CC;
#pragma unroll
    for (int k = 0; k < 6; ++k) {
        const int i = tid + k * 1024;
        if (i < TT * JJ) {
            const int t = i / JJ;
            const int j = i - t * JJ;
            lp[i] = log_probs[(size_t)t * (NN * CC) + rowbase + lab[j]] * LOG2E;
        }
    }
    __syncthreads();

    if (tid >= 64) return;          // wave 0 only; no more barriers
    const int lane = tid;

    const int tl = target_lengths[n];
    const int Lv = 2 * tl + 1;
    // lane l's slot in the unique-column row: even->blank(0), odd->1+(l>>1)
    const int slot = (lane & 1) ? (1 + (lane >> 1)) : 0;
    const bool skip = (lane & 1) && (lane >= 3) &&
                      (lab[1 + (lane >> 1)] != lab[lane >> 1]);
    const bool validl  = lane < Lv;
    const bool valid64 = 64 < Lv;
    const bool row0lane = (lane & 15) == 0;

    // alpha (log2-scaled); lane l holds l, lane 63 also holds l=64 in `e`
    float v = NEGV;
    if (lane == 0) v = lp[0];        // t=0, blank
    if (lane == 1) v = lp[1];        // t=0, first label
    float e = NEGV;

    const int ilen = input_lengths[n];
    const int Tlim = (ilen < TT) ? ilen : TT;

    for (int t = 1; t < Tlim; ++t) {
        const float u1 = dpp_up1(v, row0lane);   // v[lane-1]
        const float u2 = dpp_up1(u1, row0lane);  // v[lane-2]
        const float a2 = (lane == 0) ? NEGV : u1;
        const float a3 = skip ? u2 : NEGV;

        // l = 64 (blank, never skip) on lane 63, using OLD v (= alpha[63])
        const float lpt64 = lp[t * JJ];          // slot 0, uniform -> broadcast
        const float me = fmaxf(e, v);
        const float ne = me + log2f(exp2f(e - me) + exp2f(v - me)) + lpt64;

        const float m  = fmaxf(v, fmaxf(a2, a3));
        const float nv = m + log2f(exp2f(v - m) + exp2f(a2 - m) + exp2f(a3 - m))
                           + lp[t * JJ + slot];

        v = validl  ? nv : NEGV;
        e = valid64 ? ne : NEGV;
    }

    const int i1 = 2 * tl;
    const int i2 = 2 * tl - 1;
    const float A1 = (i1 == 64) ? __shfl(e, 63) : __shfl(v, i1);
    const float A2 = __shfl(v, i2);
    if (lane == 0) {
        const float m = fmaxf(A1, A2);
        float loss = -LN2 * (m + log2f(exp2f(A1 - m) + exp2f(A2 - m)));
        if (loss > 1e29f) loss = 0.0f;    // zero_infinity
        per_sample[n] = loss / (float)tl;
    }
}

// ---------------- Kernel 2: reduce + focal ----------------
__global__ __launch_bounds__(128) void focal_reduce_kernel(
    const float* __restrict__ per_sample, float* __restrict__ out)
{
    __shared__ float s[NN];
    int tid = threadIdx.x;
    s[tid] = per_sample[tid];
    __syncthreads();
    for (int off = NN / 2; off > 0; off >>= 1) {
        if (tid < off) s[tid] += s[tid + off];
        __syncthreads();
    }
    if (tid == 0) {
        float mean = s[0] / (float)NN;
        float pp = expf(-mean);
        float om = 1.0f - pp;
        out[0] = 0.5f * om * om * mean;   // ALPHA=0.5, GAMMA=2.0
    }
}

extern "C" void kernel_launch(void* const* d_in, const int* in_sizes, int n_in,
                              void* d_out, int out_size, void* d_ws, size_t ws_size,
                              hipStream_t stream) {
    const float* log_probs      = (const float*)d_in[0];
    const int*   targets        = (const int*)d_in[1];
    const int*   input_lengths  = (const int*)d_in[2];
    const int*   target_lengths = (const int*)d_in[3];
    float* out        = (float*)d_out;
    float* per_sample = (float*)d_ws;    // 128 floats

    ctc_fused_kernel<<<NN, 1024, 0, stream>>>(log_probs, targets, input_lengths,
                                              target_lengths, per_sample);
    focal_reduce_kernel<<<1, NN, 0, stream>>>(per_sample, out);
}